// Round 1
// 682.929 us; speedup vs baseline: 1.1917x; 1.1917x over previous
//
#include <hip/hip_runtime.h>

#define N_NODES 20000
#define N_EDGES 320000
#define DIM 256
#define H_HEADS 4

typedef _Float16 f16x8 __attribute__((ext_vector_type(8)));
typedef float f32x4v __attribute__((ext_vector_type(4)));

// ---------------- init: convert W to f16 transposed, zero counts ----------------
__global__ void k_init(const float* __restrict__ Wn, const float* __restrict__ We,
                       _Float16* __restrict__ WTn, _Float16* __restrict__ WTe,
                       unsigned int* __restrict__ counts)
{
    int i = blockIdx.x * 256 + threadIdx.x;
    if (i < DIM * DIM) {
        int n = i >> 8, k = i & 255;
        WTn[i] = (_Float16)Wn[k * DIM + n];
        WTe[i] = (_Float16)We[k * DIM + n];
    }
    if (i <= N_NODES) counts[i] = 0u;
}

// ---------------- CSR build ----------------
__global__ void k_hist(const int* __restrict__ dst, unsigned int* __restrict__ counts)
{
    int i = blockIdx.x * 256 + threadIdx.x;
    if (i < N_EDGES) atomicAdd(&counts[dst[i]], 1u);
}

// single-block exclusive scan, wave-shuffle based (3 barriers/iter)
__global__ __launch_bounds__(1024) void k_scan(unsigned int* __restrict__ counts,
                                               unsigned int* __restrict__ cursor)
{
    __shared__ unsigned int wsum[16];
    __shared__ unsigned int carry;
    const int t = threadIdx.x, lane = t & 63, wv = t >> 6;
    if (t == 0) carry = 0u;
    __syncthreads();
    for (int base = 0; base < N_NODES; base += 1024) {
        int i = base + t;
        unsigned int v = (i < N_NODES) ? counts[i] : 0u;
        unsigned int x = v;
#pragma unroll
        for (int off = 1; off < 64; off <<= 1) {
            unsigned int y = __shfl_up(x, off);
            if (lane >= off) x += y;
        }
        if (lane == 63) wsum[wv] = x;
        __syncthreads();
        if (t < 16) {
            unsigned int s = wsum[t];
#pragma unroll
            for (int off = 1; off < 16; off <<= 1) {
                unsigned int y = __shfl_up(s, off);
                if (lane >= off) s += y;
            }
            wsum[t] = s;           // inclusive scan of wave sums
        }
        __syncthreads();
        unsigned int c = carry;
        unsigned int excl = c + (wv ? wsum[wv - 1] : 0u) + x - v;
        if (i < N_NODES) { counts[i] = excl; cursor[i] = excl; }
        __syncthreads();           // all reads of carry/wsum done
        if (t == 0) carry = c + wsum[15];
        __syncthreads();           // carry visible, wsum reusable
    }
    if (t == 0) counts[N_NODES] = carry;
}

__global__ void k_scatter(const int* __restrict__ dst, unsigned int* __restrict__ cursor,
                          int* __restrict__ esort)
{
    int i = blockIdx.x * 256 + threadIdx.x;
    if (i < N_EDGES) {
        unsigned int p = atomicAdd(&cursor[dst[i]], 1u);
        esort[p] = i;
    }
}

// ---------------- node projection GEMM: ft = nfeat @ W_node (f32 out) ----------------
__global__ __launch_bounds__(256) void k_gemm_node(
    const float* __restrict__ A, const _Float16* __restrict__ WT,
    float* __restrict__ C, int M)
{
    __shared__ __align__(16) _Float16 Alds[64][40];
    const int t = threadIdx.x;
    const int m0 = blockIdx.x * 64;
    const int lane = t & 63, w = t >> 6;
    const int q = lane >> 4, c16 = lane & 15;
    const int srow = t >> 2;
    const int skb = (t & 3) * 8;
    f32x4v acc[4][4] = {};

    const int grow = m0 + srow;
    const bool valid = grow < M;
    const float* gp = A + (size_t)grow * DIM + skb;
    f32x4v v0 = {}, v1 = {};
    if (valid) {
        v0 = __builtin_nontemporal_load((const f32x4v*)gp);
        v1 = __builtin_nontemporal_load((const f32x4v*)(gp + 4));
    }

    for (int k0 = 0; k0 < DIM; k0 += 32) {
        f16x8 h8;
        h8[0]=(_Float16)v0[0]; h8[1]=(_Float16)v0[1]; h8[2]=(_Float16)v0[2]; h8[3]=(_Float16)v0[3];
        h8[4]=(_Float16)v1[0]; h8[5]=(_Float16)v1[1]; h8[6]=(_Float16)v1[2]; h8[7]=(_Float16)v1[3];
        __syncthreads();
        *(f16x8*)&Alds[srow][skb] = h8;
        __syncthreads();
        if (k0 + 32 < DIM && valid) {   // prefetch next k-step while MFMA runs
            v0 = __builtin_nontemporal_load((const f32x4v*)(gp + k0 + 32));
            v1 = __builtin_nontemporal_load((const f32x4v*)(gp + k0 + 36));
        }

        f16x8 bfr[4], afr[4];
#pragma unroll
        for (int ni = 0; ni < 4; ++ni) {
            int col = (w << 6) + (ni << 4) + c16;
            bfr[ni] = *(const f16x8*)(WT + (size_t)col * DIM + k0 + q * 8);
        }
#pragma unroll
        for (int mi = 0; mi < 4; ++mi)
            afr[mi] = *(const f16x8*)&Alds[c16 + 16 * mi][q * 8];
#pragma unroll
        for (int mi = 0; mi < 4; ++mi)
#pragma unroll
            for (int ni = 0; ni < 4; ++ni)
                acc[mi][ni] = __builtin_amdgcn_mfma_f32_16x16x32_f16(afr[mi], bfr[ni], acc[mi][ni], 0, 0, 0);
    }

#pragma unroll
    for (int mi = 0; mi < 4; ++mi) {
#pragma unroll
        for (int reg = 0; reg < 4; ++reg) {
            int row = m0 + 16 * mi + 4 * q + reg;
            if (row < M) {
#pragma unroll
                for (int ni = 0; ni < 4; ++ni) {
                    int c = (w << 6) + (ni << 4) + c16;
                    C[(size_t)row * DIM + c] = acc[mi][ni][reg];
                }
            }
        }
    }
}

// ---------------- fused edge GEMM in dst-sorted order: ftp (sorted), a (sorted) ----------------
__global__ __launch_bounds__(256) void k_gemm_edge(
    const float* __restrict__ efeat, const _Float16* __restrict__ WT,
    const float* __restrict__ ft, const int* __restrict__ src, const int* __restrict__ dst,
    const int* __restrict__ esort,
    _Float16* __restrict__ ftp, float* __restrict__ a_ws)
{
    __shared__ __align__(16) _Float16 Alds[64][40];
    __shared__ int eidx[64], ssrc[64], sdst[64];
    const int t = threadIdx.x;
    const int e0 = blockIdx.x * 64;
    const int lane = t & 63, w = t >> 6;
    const int q = lane >> 4, c16 = lane & 15;
    const int srow = t >> 2;
    const int skb = (t & 3) * 8;
    f32x4v acc[4][4] = {};

    if (t < 64) {
        int e = esort[e0 + t];
        eidx[t] = e;
        ssrc[t] = src[e];
        sdst[t] = dst[e];
    }
    __syncthreads();

    const float* gp = efeat + (size_t)eidx[srow] * DIM + skb;
    f32x4v v0 = __builtin_nontemporal_load((const f32x4v*)gp);
    f32x4v v1 = __builtin_nontemporal_load((const f32x4v*)(gp + 4));

    for (int k0 = 0; k0 < DIM; k0 += 32) {
        f16x8 h8;
        h8[0]=(_Float16)v0[0]; h8[1]=(_Float16)v0[1]; h8[2]=(_Float16)v0[2]; h8[3]=(_Float16)v0[3];
        h8[4]=(_Float16)v1[0]; h8[5]=(_Float16)v1[1]; h8[6]=(_Float16)v1[2]; h8[7]=(_Float16)v1[3];
        __syncthreads();
        *(f16x8*)&Alds[srow][skb] = h8;
        __syncthreads();
        if (k0 + 32 < DIM) {            // prefetch next k-step while MFMA runs
            v0 = __builtin_nontemporal_load((const f32x4v*)(gp + k0 + 32));
            v1 = __builtin_nontemporal_load((const f32x4v*)(gp + k0 + 36));
        }

        f16x8 bfr[4], afr[4];
#pragma unroll
        for (int ni = 0; ni < 4; ++ni) {
            int col = (w << 6) + (ni << 4) + c16;
            bfr[ni] = *(const f16x8*)(WT + (size_t)col * DIM + k0 + q * 8);
        }
#pragma unroll
        for (int mi = 0; mi < 4; ++mi)
            afr[mi] = *(const f16x8*)&Alds[c16 + 16 * mi][q * 8];
#pragma unroll
        for (int mi = 0; mi < 4; ++mi)
#pragma unroll
            for (int ni = 0; ni < 4; ++ni)
                acc[mi][ni] = __builtin_amdgcn_mfma_f32_16x16x32_f16(afr[mi], bfr[ni], acc[mi][ni], 0, 0, 0);
    }

    // epilogue: ft_prime = eft + ft[src] (stored at SORTED position); a = dot(ft_prime, ft[dst])
#pragma unroll
    for (int mi = 0; mi < 4; ++mi) {
#pragma unroll
        for (int reg = 0; reg < 4; ++reg) {
            const int r = 16 * mi + 4 * q + reg;
            const int s = e0 + r;                       // sorted position
            const float* fsrc = ft + (size_t)ssrc[r] * DIM;
            const float* fdst = ft + (size_t)sdst[r] * DIM;
            float dotp = 0.f;
#pragma unroll
            for (int ni = 0; ni < 4; ++ni) {
                int c = (w << 6) + (ni << 4) + c16;
                float v = acc[mi][ni][reg] + fsrc[c];
                ftp[(size_t)s * DIM + c] = (_Float16)v;
                dotp += v * fdst[c];
            }
            dotp += __shfl_xor(dotp, 1);
            dotp += __shfl_xor(dotp, 2);
            dotp += __shfl_xor(dotp, 4);
            dotp += __shfl_xor(dotp, 8);
            if (c16 == 0) a_ws[s * H_HEADS + w] = dotp;
        }
    }
}

// ---------------- fused softmax + aggregation: one wave per node, sequential ftp ----------------
__global__ __launch_bounds__(256) void k_agg(
    const unsigned int* __restrict__ offs, const float* __restrict__ a_ws,
    const _Float16* __restrict__ ftp, float* __restrict__ out)
{
    const int n = blockIdx.x * 4 + (threadIdx.x >> 6);
    const int lane = threadIdx.x & 63;
    const int beg = (int)offs[n], end = (int)offs[n + 1];

    // pass A: per-head max (lane handles head lane&3; stride 64 preserves head)
    float m = -1e30f;
    for (int j = beg * 4 + lane; j < end * 4; j += 64)
        m = fmaxf(m, a_ws[j]);
    m = fmaxf(m, __shfl_xor(m, 4));
    m = fmaxf(m, __shfl_xor(m, 8));
    m = fmaxf(m, __shfl_xor(m, 16));
    m = fmaxf(m, __shfl_xor(m, 32));

    // pass B: per-head sum of exp
    float sm = 0.f;
    for (int j = beg * 4 + lane; j < end * 4; j += 64)
        sm += __expf(a_ws[j] - m);
    sm += __shfl_xor(sm, 4);
    sm += __shfl_xor(sm, 8);
    sm += __shfl_xor(sm, 16);
    sm += __shfl_xor(sm, 32);

    // pass C: weighted aggregation, 2 edges (1 KB) per wave iteration
    const int half = lane >> 5;          // edge parity
    const int cb = (lane & 31) * 8;      // col base (8 f16 per lane)
    const int hc = cb >> 6;              // head of these cols
    const float mh = __shfl(m, hc);
    const float sh = __shfl(sm, hc);
    const float inv = (end > beg) ? 0.125f / sh : 0.f;

    float acc[8] = {};
    for (int j = beg + half; j < end; j += 2) {
        float wj = __expf(a_ws[j * H_HEADS + hc] - mh);
        f16x8 d = *(const f16x8*)(ftp + (size_t)j * DIM + cb);
#pragma unroll
        for (int k = 0; k < 8; ++k) acc[k] += wj * (float)d[k];
    }
#pragma unroll
    for (int k = 0; k < 8; ++k) acc[k] += __shfl_xor(acc[k], 32);

    if (half == 0) {
        float4 o0 = make_float4(acc[0] * inv, acc[1] * inv, acc[2] * inv, acc[3] * inv);
        float4 o1 = make_float4(acc[4] * inv, acc[5] * inv, acc[6] * inv, acc[7] * inv);
        *(float4*)(out + (size_t)n * DIM + cb)     = o0;
        *(float4*)(out + (size_t)n * DIM + cb + 4) = o1;
    }
}

// ---------------- launch ----------------
extern "C" void kernel_launch(void* const* d_in, const int* in_sizes, int n_in,
                              void* d_out, int out_size, void* d_ws, size_t ws_size,
                              hipStream_t stream)
{
    const float* nfeat = (const float*)d_in[0];
    const float* efeat = (const float*)d_in[1];
    const int* src = (const int*)d_in[2];
    const int* dst = (const int*)d_in[3];
    const float* Wn = (const float*)d_in[4];
    const float* We = (const float*)d_in[5];
    float* out = (float*)d_out;

    char* ws = (char*)d_ws;
    size_t off = 0;
    auto alloc = [&](size_t bytes) -> void* {
        off = (off + 255) & ~(size_t)255;
        void* p = ws + off;
        off += bytes;
        return p;
    };

    _Float16* WTn = (_Float16*)alloc((size_t)DIM * DIM * 2);
    _Float16* WTe = (_Float16*)alloc((size_t)DIM * DIM * 2);
    float* ft = (float*)alloc((size_t)N_NODES * DIM * 4);
    _Float16* ftp = (_Float16*)alloc((size_t)N_EDGES * DIM * 2);
    float* a_ws = (float*)alloc((size_t)N_EDGES * H_HEADS * 4);
    unsigned int* counts = (unsigned int*)alloc((size_t)(N_NODES + 1) * 4);
    unsigned int* cursor = (unsigned int*)alloc((size_t)N_NODES * 4);
    int* esort = (int*)alloc((size_t)N_EDGES * 4);

    k_init<<<256, 256, 0, stream>>>(Wn, We, WTn, WTe, counts);
    k_hist<<<(N_EDGES + 255) / 256, 256, 0, stream>>>(dst, counts);
    k_scan<<<1, 1024, 0, stream>>>(counts, cursor);
    k_scatter<<<(N_EDGES + 255) / 256, 256, 0, stream>>>(dst, cursor, esort);
    k_gemm_node<<<(N_NODES + 63) / 64, 256, 0, stream>>>(nfeat, WTn, ft, N_NODES);
    k_gemm_edge<<<N_EDGES / 64, 256, 0, stream>>>(efeat, WTe, ft, src, dst, esort, ftp, a_ws);
    k_agg<<<N_NODES / 4, 256, 0, stream>>>(counts, a_ws, ftp, out);
}